// Round 1
// baseline (5022.567 us; speedup 1.0000x reference)
//
#include <hip/hip_runtime.h>

typedef __attribute__((ext_vector_type(8))) short short8;
typedef __attribute__((ext_vector_type(4))) float f32x4;

__device__ __forceinline__ unsigned short f2bf(float f) {
  unsigned u = __builtin_bit_cast(unsigned, f);
  u += 0x7fffu + ((u >> 16) & 1u);           // round-to-nearest-even
  return (unsigned short)(u >> 16);
}

__device__ __forceinline__ float fast_tanh(float x) {
  float e = __expf(2.0f * x);
  return 1.0f - __fdividef(2.0f, e + 1.0f);
}

// ---------------------------------------------------------------------------
// Generic C = A(fp32)[M,K] @ B(fp32)[K,N] + bias, via bf16 MFMA 16x16x32.
// 128x128 tile, BK=32, 256 threads (4 waves in 2x2, each 64x64 = 4x4 frags).
// LDS holds A- and B-tiles pre-swizzled into MFMA fragment order.
// ---------------------------------------------------------------------------
__global__ __launch_bounds__(256) void gemm_bias(
    const float* __restrict__ A, const float* __restrict__ B,
    const float* __restrict__ bias, float* __restrict__ C,
    int M, int N, int K)
{
  __shared__ short a_lds[128 * 32];  // [(mt*64 + lane)*8 + j]
  __shared__ short b_lds[32 * 128];  // [(nt*64 + lane)*8 + j]
  const int tid = threadIdx.x;
  const int lane = tid & 63;
  const int w = tid >> 6;
  const int wm = w >> 1, wn = w & 1;
  const long m0 = (long)blockIdx.x * 128;
  const int n0 = blockIdx.y * 128;

  f32x4 acc[4][4];
#pragma unroll
  for (int i = 0; i < 4; ++i)
#pragma unroll
    for (int j = 0; j < 4; ++j) acc[i][j] = (f32x4){0.f, 0.f, 0.f, 0.f};

  for (int k0 = 0; k0 < K; k0 += 32) {
    // ---- stage A tile: 128 rows x 32 k. task = (row, kgroup-of-8) ----
#pragma unroll
    for (int it = 0; it < 2; ++it) {
      int tsk = tid + (it << 8);
      int r = tsk >> 2;        // 0..127 row in tile
      int kg = tsk & 3;        // k-group of 8
      const float* src = A + (m0 + r) * (long)K + (k0 + kg * 8);
      float4 f0 = *(const float4*)src;
      float4 f1 = *(const float4*)(src + 4);
      short8 v;
      v[0] = f2bf(f0.x); v[1] = f2bf(f0.y); v[2] = f2bf(f0.z); v[3] = f2bf(f0.w);
      v[4] = f2bf(f1.x); v[5] = f2bf(f1.y); v[6] = f2bf(f1.z); v[7] = f2bf(f1.w);
      // frag position: lane = kg*16 + (r&15), j = k&7, tile mt = r>>4
      *(short8*)&a_lds[(((r >> 4) * 64) + kg * 16 + (r & 15)) * 8] = v;
    }
    // ---- stage B tile: 32 k x 128 n. thread owns one column, 8 k's ----
#pragma unroll
    for (int rep = 0; rep < 2; ++rep) {
      int nl = tid & 127;
      int kg = (tid >> 7) + rep * 2;   // 0..3
      const float* src = B + (long)(k0 + kg * 8) * N + (n0 + nl);
      short8 v;
#pragma unroll
      for (int r2 = 0; r2 < 8; ++r2) v[r2] = f2bf(src[(long)r2 * N]);
      *(short8*)&b_lds[(((nl >> 4) * 64) + kg * 16 + (nl & 15)) * 8] = v;
    }
    __syncthreads();
    short8 af[4], bfr[4];
#pragma unroll
    for (int mt = 0; mt < 4; ++mt)
      af[mt] = *(const short8*)&a_lds[((wm * 4 + mt) * 64 + lane) * 8];
#pragma unroll
    for (int nt = 0; nt < 4; ++nt)
      bfr[nt] = *(const short8*)&b_lds[((wn * 4 + nt) * 64 + lane) * 8];
#pragma unroll
    for (int mt = 0; mt < 4; ++mt)
#pragma unroll
      for (int nt = 0; nt < 4; ++nt)
        acc[mt][nt] = __builtin_amdgcn_mfma_f32_16x16x32_bf16(
            af[mt], bfr[nt], acc[mt][nt], 0, 0, 0);
    __syncthreads();
  }
  // ---- epilogue: C/D layout col=lane&15, row=(lane>>4)*4+r ----
#pragma unroll
  for (int nt = 0; nt < 4; ++nt) {
    int col = n0 + wn * 64 + nt * 16 + (lane & 15);
    float bv = bias[col];
#pragma unroll
    for (int mt = 0; mt < 4; ++mt) {
      long row = m0 + wm * 64 + mt * 16 + ((lane >> 4) * 4);
#pragma unroll
      for (int r = 0; r < 4; ++r)
        C[(row + r) * (long)N + col] = acc[mt][nt][r] + bv;
    }
  }
}

// ---------------------------------------------------------------------------
// Persistent RNN scan. 32 workgroups x 256 threads; wg g owns h-columns
// [g*32, g*32+32). W_hh column slice lives in LDS (bf16, fragment order).
// xs = states region of d_out: holds Xproj[t] on entry, overwritten with h_t.
// hbuf = bf16 double buffer of h in ws. flags = per-step barrier counters.
// ---------------------------------------------------------------------------
__global__ __launch_bounds__(256) void rnn_scan(
    const float* __restrict__ Whh, float* __restrict__ xs,
    unsigned short* __restrict__ hbuf, int* __restrict__ flags)
{
  __shared__ short wlds[1024 * 32];  // 64 KB: [((ks*2+nt)*64 + lane)*8 + j]
  const int H = 1024;
  const int tid = threadIdx.x, lane = tid & 63, w = tid >> 6;
  const int n0 = blockIdx.x * 32;

  // ---- stage W_hh[:, n0:n0+32] once, fragment-ordered ----
  for (int ks = w * 8; ks < w * 8 + 8; ++ks) {
#pragma unroll
    for (int p = 0; p < 2; ++p) {
      int kg = p * 2 + (lane >> 5);     // 0..3
      int nl = lane & 31;
      const float* src = Whh + (long)(ks * 32 + kg * 8) * H + (n0 + nl);
      short8 v;
#pragma unroll
      for (int r = 0; r < 8; ++r) v[r] = f2bf(src[(long)r * H]);
      int nt = nl >> 4;
      *(short8*)&wlds[(((ks * 2 + nt) * 64) + kg * 16 + (nl & 15)) * 8] = v;
    }
  }
  __syncthreads();

  const int mrow = w * 16 + (lane & 15);          // A-frag row (batch)
  const int crow = w * 16 + ((lane >> 4) << 2);   // C-frag row base
  const int ncol = lane & 15;

  for (int t = 0; t < 512; ++t) {
    const int cur = t & 1;
    float* xrow = xs + (long)t * 64 * H;
    float xp0[4], xp1[4];
#pragma unroll
    for (int r = 0; r < 4; ++r) {
      xp0[r] = xrow[(crow + r) * H + n0 + ncol];
      xp1[r] = xrow[(crow + r) * H + n0 + 16 + ncol];
    }
    f32x4 acc0 = {0.f, 0.f, 0.f, 0.f}, acc1 = {0.f, 0.f, 0.f, 0.f};
    const unsigned short* hrow = hbuf + (long)cur * 64 * H + (long)mrow * H + ((lane >> 4) * 8);
#pragma unroll 8
    for (int ks = 0; ks < 32; ++ks) {
      short8 a = *(const short8*)(hrow + ks * 32);
      short8 b0 = *(const short8*)&wlds[((ks * 2 + 0) * 64 + lane) * 8];
      short8 b1 = *(const short8*)&wlds[((ks * 2 + 1) * 64 + lane) * 8];
      acc0 = __builtin_amdgcn_mfma_f32_16x16x32_bf16(a, b0, acc0, 0, 0, 0);
      acc1 = __builtin_amdgcn_mfma_f32_16x16x32_bf16(a, b1, acc1, 0, 0, 0);
    }
    unsigned short* hnrow = hbuf + (long)(cur ^ 1) * 64 * H;
#pragma unroll
    for (int r = 0; r < 4; ++r) {
      float h0 = fast_tanh(acc0[r] + xp0[r]);
      float h1 = fast_tanh(acc1[r] + xp1[r]);
      xrow[(crow + r) * H + n0 + ncol] = h0;            // states (fp32)
      xrow[(crow + r) * H + n0 + 16 + ncol] = h1;
      hnrow[(long)(crow + r) * H + n0 + ncol] = f2bf(h0);       // next-step A
      hnrow[(long)(crow + r) * H + n0 + 16 + ncol] = f2bf(h1);
    }
    // ---- device-scope barrier (cross-XCD coherent) ----
    __syncthreads();  // drains each wave's vmcnt before s_barrier
    if (tid == 0) {
      __hip_atomic_fetch_add(&flags[t], 1, __ATOMIC_ACQ_REL, __HIP_MEMORY_SCOPE_AGENT);
      while (__hip_atomic_load(&flags[t], __ATOMIC_RELAXED, __HIP_MEMORY_SCOPE_AGENT) < 32)
        __builtin_amdgcn_s_sleep(2);
      __threadfence();  // acquire: invalidate L1/L2 before reading remote h
    }
    __syncthreads();
  }
}

extern "C" void kernel_launch(void* const* d_in, const int* in_sizes, int n_in,
                              void* d_out, int out_size, void* d_ws, size_t ws_size,
                              hipStream_t stream)
{
  const float* X   = (const float*)d_in[0];  // [512,64,512]
  const float* Wxh = (const float*)d_in[1];  // [512,1024]
  const float* Whh = (const float*)d_in[2];  // [1024,1024]
  const float* bh  = (const float*)d_in[3];  // [1024]
  const float* Whq = (const float*)d_in[4];  // [1024,512]
  const float* bq  = (const float*)d_in[5];  // [512]

  float* outputs = (float*)d_out;                       // [512,64,512]
  float* states  = outputs + (long)512 * 64 * 512;      // [512,64,1024]

  unsigned short* hbuf = (unsigned short*)d_ws;                 // 2*64*1024 bf16
  int* flags = (int*)((char*)d_ws + (size_t)2 * 64 * 1024 * 2); // 512 ints

  // zero h0 (both buffers) + barrier flags
  hipMemsetAsync(d_ws, 0, (size_t)2 * 64 * 1024 * 2 + 512 * 4, stream);

  // phase 1: Xproj = X @ W_xh + b_h  -> states region (consumed in-place)
  dim3 g1(32768 / 128, 1024 / 128);
  gemm_bias<<<g1, 256, 0, stream>>>(X, Wxh, bh, states, 32768, 1024, 512);

  // phase 2: sequential scan, overwrites states with h_t
  rnn_scan<<<32, 256, 0, stream>>>(Whh, states, hbuf, flags);

  // phase 3: outputs = states @ W_hq + b_q
  dim3 g3(32768 / 128, 512 / 128);
  gemm_bias<<<g3, 256, 0, stream>>>(states, Whq, bq, outputs, 32768, 512, 1024);
}

// Round 2
// 4919.096 us; speedup vs baseline: 1.0210x; 1.0210x over previous
//
#include <hip/hip_runtime.h>

typedef __attribute__((ext_vector_type(8))) short short8;
typedef __attribute__((ext_vector_type(4))) float f32x4;
typedef unsigned long long u64;

__device__ __forceinline__ unsigned short f2bf(float f) {
  unsigned u = __builtin_bit_cast(unsigned, f);
  u += 0x7fffu + ((u >> 16) & 1u);           // round-to-nearest-even
  return (unsigned short)(u >> 16);
}

__device__ __forceinline__ float fast_tanh(float x) {
  float e = __expf(2.0f * x);
  return 1.0f - __fdividef(2.0f, e + 1.0f);
}

// ---------------------------------------------------------------------------
// Generic C = A(fp32)[M,K] @ B(fp32)[K,N] + bias, via bf16 MFMA 16x16x32.
// 128x128 tile, BK=32, 256 threads (4 waves in 2x2, each 64x64 = 4x4 frags).
// ---------------------------------------------------------------------------
__global__ __launch_bounds__(256) void gemm_bias(
    const float* __restrict__ A, const float* __restrict__ B,
    const float* __restrict__ bias, float* __restrict__ C,
    int M, int N, int K)
{
  __shared__ short a_lds[128 * 32];
  __shared__ short b_lds[32 * 128];
  const int tid = threadIdx.x;
  const int lane = tid & 63;
  const int w = tid >> 6;
  const int wm = w >> 1, wn = w & 1;
  const long m0 = (long)blockIdx.x * 128;
  const int n0 = blockIdx.y * 128;

  f32x4 acc[4][4];
#pragma unroll
  for (int i = 0; i < 4; ++i)
#pragma unroll
    for (int j = 0; j < 4; ++j) acc[i][j] = (f32x4){0.f, 0.f, 0.f, 0.f};

  for (int k0 = 0; k0 < K; k0 += 32) {
#pragma unroll
    for (int it = 0; it < 2; ++it) {
      int tsk = tid + (it << 8);
      int r = tsk >> 2;
      int kg = tsk & 3;
      const float* src = A + (m0 + r) * (long)K + (k0 + kg * 8);
      float4 f0 = *(const float4*)src;
      float4 f1 = *(const float4*)(src + 4);
      short8 v;
      v[0] = f2bf(f0.x); v[1] = f2bf(f0.y); v[2] = f2bf(f0.z); v[3] = f2bf(f0.w);
      v[4] = f2bf(f1.x); v[5] = f2bf(f1.y); v[6] = f2bf(f1.z); v[7] = f2bf(f1.w);
      *(short8*)&a_lds[(((r >> 4) * 64) + kg * 16 + (r & 15)) * 8] = v;
    }
#pragma unroll
    for (int rep = 0; rep < 2; ++rep) {
      int nl = tid & 127;
      int kg = (tid >> 7) + rep * 2;
      const float* src = B + (long)(k0 + kg * 8) * N + (n0 + nl);
      short8 v;
#pragma unroll
      for (int r2 = 0; r2 < 8; ++r2) v[r2] = f2bf(src[(long)r2 * N]);
      *(short8*)&b_lds[(((nl >> 4) * 64) + kg * 16 + (nl & 15)) * 8] = v;
    }
    __syncthreads();
    short8 af[4], bfr[4];
#pragma unroll
    for (int mt = 0; mt < 4; ++mt)
      af[mt] = *(const short8*)&a_lds[((wm * 4 + mt) * 64 + lane) * 8];
#pragma unroll
    for (int nt = 0; nt < 4; ++nt)
      bfr[nt] = *(const short8*)&b_lds[((wn * 4 + nt) * 64 + lane) * 8];
#pragma unroll
    for (int mt = 0; mt < 4; ++mt)
#pragma unroll
      for (int nt = 0; nt < 4; ++nt)
        acc[mt][nt] = __builtin_amdgcn_mfma_f32_16x16x32_bf16(
            af[mt], bfr[nt], acc[mt][nt], 0, 0, 0);
    __syncthreads();
  }
#pragma unroll
  for (int nt = 0; nt < 4; ++nt) {
    int col = n0 + wn * 64 + nt * 16 + (lane & 15);
    float bv = bias[col];
#pragma unroll
    for (int mt = 0; mt < 4; ++mt) {
      long row = m0 + wm * 64 + mt * 16 + ((lane >> 4) * 4);
#pragma unroll
      for (int r = 0; r < 4; ++r)
        C[(row + r) * (long)N + col] = acc[mt][nt][r] + bv;
    }
  }
}

// ---------------------------------------------------------------------------
// Persistent RNN scan, fence-free coherence.
// 32 wgs x 256 threads; wg g owns h-columns [g*32, g*32+32).
// All cross-wg traffic (hbuf double buffer, flags) via relaxed AGENT-scope
// atomics (sc0/sc1 -> LLC-coherent, no L2 flushes). Barrier: per-wg flag
// store + 32 parallel pollers. h_t bounced through LDS to get 8B coherent
// stores. xs holds Xproj on entry, overwritten with states (plain stores).
// ---------------------------------------------------------------------------
__global__ __launch_bounds__(256) void rnn_scan(
    const float* __restrict__ Whh, float* __restrict__ xs,
    unsigned short* __restrict__ hbuf, int* __restrict__ flags)
{
  __shared__ short wlds[1024 * 32];   // 64 KB, MFMA B-frag order
  __shared__ short hstage[64 * 32];   // 4 KB h_t slice for coalesced stores
  const int H = 1024;
  const int tid = threadIdx.x, lane = tid & 63, w = tid >> 6;
  const int g = blockIdx.x;
  const int n0 = g * 32;

  // ---- stage W_hh[:, n0:n0+32] once, fragment-ordered ----
  for (int ks = w * 8; ks < w * 8 + 8; ++ks) {
#pragma unroll
    for (int p = 0; p < 2; ++p) {
      int kg = p * 2 + (lane >> 5);
      int nl = lane & 31;
      const float* src = Whh + (long)(ks * 32 + kg * 8) * H + (n0 + nl);
      short8 v;
#pragma unroll
      for (int r = 0; r < 8; ++r) v[r] = f2bf(src[(long)r * H]);
      int nt = nl >> 4;
      *(short8*)&wlds[(((ks * 2 + nt) * 64) + kg * 16 + (nl & 15)) * 8] = v;
    }
  }
  __syncthreads();

  const int mrow = w * 16 + (lane & 15);          // A-frag row (batch)
  const int crow = w * 16 + ((lane >> 4) << 2);   // C-frag row base
  const int ncol = lane & 15;
  const int koff = (lane >> 4) * 8;

  // repack task: chunk c covers hstage row (c>>3), 4 cols at (c&7)*4
  const int c0 = tid * 2;
  const int rp_row0 = c0 >> 3, rp_cg0 = c0 & 7;
  const int rp_row1 = (c0 + 1) >> 3, rp_cg1 = (c0 + 1) & 7;

  union Frag { u64 q[2]; short8 s; };

  for (int t = 0; t < 512; ++t) {
    const int cur = t & 1;
    float* xrow = xs + (long)t * 64 * H;
    float xp0[4], xp1[4];
#pragma unroll
    for (int r = 0; r < 4; ++r) {
      xp0[r] = xrow[(crow + r) * H + n0 + ncol];
      xp1[r] = xrow[(crow + r) * H + n0 + 16 + ncol];
    }
    const u64* h64 = (const u64*)(hbuf + (size_t)cur * 64 * H + (size_t)mrow * H + koff);
    f32x4 acc0 = {0.f, 0.f, 0.f, 0.f}, acc1 = {0.f, 0.f, 0.f, 0.f};
#pragma unroll
    for (int ks = 0; ks < 32; ++ks) {
      Frag a;
      a.q[0] = __hip_atomic_load(h64 + (size_t)ks * 8,     __ATOMIC_RELAXED, __HIP_MEMORY_SCOPE_AGENT);
      a.q[1] = __hip_atomic_load(h64 + (size_t)ks * 8 + 1, __ATOMIC_RELAXED, __HIP_MEMORY_SCOPE_AGENT);
      short8 b0 = *(const short8*)&wlds[((ks * 2 + 0) * 64 + lane) * 8];
      short8 b1 = *(const short8*)&wlds[((ks * 2 + 1) * 64 + lane) * 8];
      acc0 = __builtin_amdgcn_mfma_f32_16x16x32_bf16(a.s, b0, acc0, 0, 0, 0);
      acc1 = __builtin_amdgcn_mfma_f32_16x16x32_bf16(a.s, b1, acc1, 0, 0, 0);
    }
    // tanh, states (plain fp32), stage bf16 slice in LDS
#pragma unroll
    for (int r = 0; r < 4; ++r) {
      float h0 = fast_tanh(acc0[r] + xp0[r]);
      float h1 = fast_tanh(acc1[r] + xp1[r]);
      xrow[(crow + r) * H + n0 + ncol] = h0;
      xrow[(crow + r) * H + n0 + 16 + ncol] = h1;
      hstage[(crow + r) * 32 + ncol] = (short)f2bf(h0);
      hstage[(crow + r) * 32 + ncol + 16] = (short)f2bf(h1);
    }
    __syncthreads();   // hstage visible to repack
    // coalesced coherent 8B stores of next-h slice
    unsigned short* hn = hbuf + (size_t)(cur ^ 1) * 64 * H;
    {
      u64 v0 = *(const u64*)&hstage[rp_row0 * 32 + rp_cg0 * 4];
      u64 v1 = *(const u64*)&hstage[rp_row1 * 32 + rp_cg1 * 4];
      __hip_atomic_store((u64*)(hn + (size_t)rp_row0 * H + n0 + rp_cg0 * 4), v0,
                         __ATOMIC_RELAXED, __HIP_MEMORY_SCOPE_AGENT);
      __hip_atomic_store((u64*)(hn + (size_t)rp_row1 * H + n0 + rp_cg1 * 4), v1,
                         __ATOMIC_RELAXED, __HIP_MEMORY_SCOPE_AGENT);
    }
    __syncthreads();   // drains vmcnt -> h stores are LLC-visible
    if (tid == 0)
      __hip_atomic_store(&flags[g], t + 1, __ATOMIC_RELAXED, __HIP_MEMORY_SCOPE_AGENT);
    if (tid < 32) {
      while (__hip_atomic_load(&flags[tid], __ATOMIC_RELAXED, __HIP_MEMORY_SCOPE_AGENT) < t + 1) {}
    }
    __syncthreads();   // all 32 peers arrived; safe to read hbuf[cur^1]
  }
}

extern "C" void kernel_launch(void* const* d_in, const int* in_sizes, int n_in,
                              void* d_out, int out_size, void* d_ws, size_t ws_size,
                              hipStream_t stream)
{
  const float* X   = (const float*)d_in[0];  // [512,64,512]
  const float* Wxh = (const float*)d_in[1];  // [512,1024]
  const float* Whh = (const float*)d_in[2];  // [1024,1024]
  const float* bh  = (const float*)d_in[3];  // [1024]
  const float* Whq = (const float*)d_in[4];  // [1024,512]
  const float* bq  = (const float*)d_in[5];  // [512]

  float* outputs = (float*)d_out;                       // [512,64,512]
  float* states  = outputs + (long)512 * 64 * 512;      // [512,64,1024]

  unsigned short* hbuf = (unsigned short*)d_ws;                 // 2*64*1024 bf16
  int* flags = (int*)((char*)d_ws + (size_t)2 * 64 * 1024 * 2); // 32 ints

  hipMemsetAsync(d_ws, 0, (size_t)2 * 64 * 1024 * 2 + 512 * 4, stream);

  // phase 1: Xproj = X @ W_xh + b_h  -> states region (consumed in-place)
  dim3 g1(32768 / 128, 1024 / 128);
  gemm_bias<<<g1, 256, 0, stream>>>(X, Wxh, bh, states, 32768, 1024, 512);

  // phase 2: sequential scan, overwrites states with h_t
  rnn_scan<<<32, 256, 0, stream>>>(Whh, states, hbuf, flags);

  // phase 3: outputs = states @ W_hq + b_q
  dim3 g3(32768 / 128, 512 / 128);
  gemm_bias<<<g3, 256, 0, stream>>>(states, Whq, bq, outputs, 32768, 512, 1024);
}